// Round 5
// baseline (2312.930 us; speedup 1.0000x reference)
//
#include <hip/hip_runtime.h>

// Round 18: make k_scan2p's weights fit the register budget.
//  Model (R13..R17 consistent): per-wave weight set (512B/thread = 128 VGPR)
//  never stays resident -> ~256KB/block/step streams via scratch/L1/L2
//  (~128 B/cy/CU) -> ~2000cy/step. Codegen pins (R15-R17) all failed;
//  demand must shrink. New shape: 1024 thr / 16 waves, each wave N=32
//  (nt=2) -> weights 256B/thread = 64 VGPR, arch ~60 more = fits the
//  128-reg budget @4 waves/SIMD. Gate combine via LDS preact[4][520] f32
//  (+1 barrier); biases from LDS. vmcnt(4) 4-op/step protocol unchanged;
//  16 per-wave flags/block. Waves 8-15 duplicate the gate/publish stage
//  (same values, same addresses) to keep per-wave VMEM counts uniform.

typedef _Float16 f16x8  __attribute__((ext_vector_type(8)));
typedef float    f32x4  __attribute__((ext_vector_type(4)));

#define DEVI static __device__ __forceinline__

constexpr int   T1c   = 20;
constexpr int   EMBc  = 32;
constexpr int   H1c   = 64;
constexpr int   LMAXc = 1024;
constexpr int   VOCABc= 85;
constexpr int   Ntot  = 24832;           // sum of lengths
constexpr int   NTc   = Ntot * T1c;      // 496640
constexpr int   R2c   = 32 * LMAXc;      // 32768
constexpr float EPSc  = 1e-5f;

DEVI float sigm(float x)   { return 1.f / (1.f + __expf(-x)); }
DEVI float tanhf_(float x) { return 1.f - 2.f / (1.f + __expf(2.f * x)); }

DEVI void barrier_lds() {                // barrier draining LDS only (not vmcnt)
    asm volatile("s_waitcnt lgkmcnt(0)\n\ts_barrier" ::: "memory");
}
DEVI void drain_vmem() {
    asm volatile("s_waitcnt vmcnt(0)" ::: "memory");
}

// ---------------- prep: LSTM1 combined fp16 [4][256][128] = [Wih|pad|Whh]
__global__ void __launch_bounds__(256)
k_prepw1(const float* __restrict__ Wih0, const float* __restrict__ Whh0,
         const float* __restrict__ WihS, const float* __restrict__ WhhS,
         _Float16* __restrict__ out)
{
    int i = blockIdx.x * 256 + threadIdx.x;
    if (i >= 4 * 256 * 128) return;
    int l = i >> 15, rem = i & 32767, r = rem >> 7, k = rem & 127;
    float v;
    if (l == 0) {
        if (k < 32)      v = Wih0[r * 32 + k];
        else if (k < 64) v = 0.f;
        else             v = Whh0[r * 64 + (k - 64)];
    } else {
        if (k < 64)      v = WihS[((l - 1) * 256 + r) * 64 + k];
        else             v = WhhS[((l - 1) * 256 + r) * 64 + (k - 64)];
    }
    out[i] = (_Float16)v;
}

// ---------------- prep: LSTM2 wih16 [4][512][128] (l0 zero-padded) + whh16
// also resets pipeline flags: [0..511] real -> 0, [512..1023] dummy -> INT_MAX
__global__ void __launch_bounds__(256)
k_prepw2(const float* __restrict__ Wih0, const float* __restrict__ WihS,
         const float* __restrict__ Whh0, const float* __restrict__ WhhS,
         _Float16* __restrict__ wih, _Float16* __restrict__ whh,
         int* __restrict__ flags)
{
    int i = blockIdx.x * 256 + threadIdx.x;
    if (i < 1024) flags[i] = (i < 512) ? 0 : 0x7fffffff;
    if (i >= 2 * 4 * 512 * 128) return;
    int half = i >> 18, rem = i & 262143;
    int l = rem >> 16, r = (rem >> 7) & 511, k = rem & 127;
    if (half == 0) {
        float v = (l == 0) ? ((k < 64) ? Wih0[r * 64 + k] : 0.f)
                           : WihS[((l - 1) * 512 + r) * 128 + k];
        wih[rem] = (_Float16)v;
    } else {
        float v = (l == 0) ? Whh0[r * 128 + k]
                           : WhhS[((l - 1) * 512 + r) * 128 + k];
        whh[rem] = (_Float16)v;
    }
}

// ---------------- LSTM1: embed + 4 layers fused, one kernel. 32 samples/WG,
// 256 thr = 4 waves. Uniform K=128 body ([x(64, l0 zero-padded)|h(64)]).
__global__ void __launch_bounds__(256)
k_scan1all(const int* __restrict__ atoms, const float* __restrict__ ew,
           const _Float16* __restrict__ W16all,
           const float* __restrict__ b0, const float* __restrict__ bS,
           _Float16* __restrict__ seq, float* __restrict__ dacc)
{
    constexpr int SX = 136;
    __shared__ alignas(16) _Float16 xh[32 * SX];     // 8.7 KB
    __shared__ float ewl[VOCABc * EMBc];             // 10.9 KB
    __shared__ int   aidl[32 * T1c];                 // 2.5 KB

    const int tid  = threadIdx.x;
    const int lane = tid & 63;
    const int wv   = tid >> 6;
    const int l16  = lane & 15;
    const int quad = lane >> 4;
    const int n0   = blockIdx.x * 32;
    const int d    = wv * 16 + l16;

    for (int i = tid; i < VOCABc * EMBc; i += 256) ewl[i] = ew[i];
    for (int i = tid; i < 32 * T1c; i += 256) aidl[i] = atoms[n0 * T1c + i];

    float daccv[2][4];
#pragma unroll
    for (int mt = 0; mt < 2; ++mt)
#pragma unroll
        for (int r = 0; r < 4; ++r) daccv[mt][r] = 0.f;

    __syncthreads();

#pragma unroll 1
    for (int l = 0; l < 4; ++l) {
        const _Float16* W16  = W16all + (size_t)l * 256 * 128;
        const float*    bptr = (l == 0) ? b0 : bS + (l - 1) * 256;

        float bias[4];
#pragma unroll
        for (int g = 0; g < 4; ++g) bias[g] = bptr[g * 64 + d];

        f16x8 wF[4][4];
#pragma unroll
        for (int kc = 0; kc < 4; ++kc) {
            const int kb = kc * 32 + quad * 8;
#pragma unroll
            for (int g = 0; g < 4; ++g)
                wF[kc][g] = *(const f16x8*)&W16[(size_t)(g * 64 + d) * 128 + kb];
        }

        f32x4 c[2];
        c[0] = {1.f, 1.f, 1.f, 1.f};
        c[1] = {1.f, 1.f, 1.f, 1.f};

        drain_vmem();            // prev layer's seq stores complete (same CU)
        __syncthreads();

        // h(t=-1) = 1; layer 0: zero x cols [32,64) once (zero weights there)
#pragma unroll
        for (int mt = 0; mt < 2; ++mt)
#pragma unroll
            for (int r = 0; r < 4; ++r)
                xh[(mt * 16 + quad * 4 + r) * SX + 64 + d] = (_Float16)1.0f;
        if (l == 0)
            for (int idx = tid; idx < 32 * 32; idx += 256) {
                int s = idx >> 5, e = idx & 31;
                xh[s * SX + 32 + e] = (_Float16)0.f;
            }

#pragma unroll 1
        for (int t = 0; t < T1c; ++t) {
            if (l == 0) {
                for (int idx = tid; idx < 32 * 32; idx += 256) {
                    int s = idx >> 5, e = idx & 31;
                    int id = aidl[s * T1c + t];
                    xh[s * SX + e] = (_Float16)(ewl[id * EMBc + e] * (float)id);
                }
            } else {
                for (int idx = tid; idx < 32 * 8; idx += 256) {
                    int s = idx >> 3, k8 = idx & 7;
                    *(f16x8*)&xh[s * SX + k8 * 8] =
                        *(const f16x8*)&seq[((size_t)(n0 + s) * T1c + t) * H1c + k8 * 8];
                }
            }
            __syncthreads();

            f32x4 acc[2][4];
#pragma unroll
            for (int mt = 0; mt < 2; ++mt)
#pragma unroll
                for (int g = 0; g < 4; ++g)
                    acc[mt][g] = {bias[g], bias[g], bias[g], bias[g]};

#pragma unroll
            for (int kc = 0; kc < 4; ++kc) {
                const int kb = kc * 32 + quad * 8;
                f16x8 ah[2];
#pragma unroll
                for (int mt = 0; mt < 2; ++mt)
                    ah[mt] = *(const f16x8*)&xh[(mt * 16 + l16) * SX + kb];
#pragma unroll
                for (int g = 0; g < 4; ++g)
#pragma unroll
                    for (int mt = 0; mt < 2; ++mt)
                        acc[mt][g] = __builtin_amdgcn_mfma_f32_16x16x32_f16(ah[mt], wF[kc][g], acc[mt][g], 0, 0, 0);
            }
            __syncthreads();

#pragma unroll
            for (int mt = 0; mt < 2; ++mt)
#pragma unroll
                for (int r = 0; r < 4; ++r) {
                    float iv = sigm(acc[mt][0][r]);
                    float fv = sigm(acc[mt][1][r]);
                    float gv = tanhf_(acc[mt][2][r]);
                    float ov = sigm(acc[mt][3][r]);
                    float cv = fv * c[mt][r] + iv * gv;
                    c[mt][r] = cv;
                    float hv = ov * tanhf_(cv);
                    _Float16 hf = (_Float16)hv;
                    int s = mt * 16 + quad * 4 + r;
                    xh[s * SX + 64 + d] = hf;
                    if (l < 3)
                        seq[((size_t)(n0 + s) * T1c + t) * H1c + d] = hf;
                    if (t == T1c - 1)
                        daccv[mt][r] += 0.25f * (hv + cv);
                }
        }
    }
#pragma unroll
    for (int mt = 0; mt < 2; ++mt)
#pragma unroll
        for (int r = 0; r < 4; ++r) {
            int s = mt * 16 + quad * 4 + r;
            dacc[(size_t)(n0 + s) * H1c + d] = daccv[mt][r];
        }
}

// ---------------- BN2 stats
__global__ void __launch_bounds__(256)
k_bn2_stats(const int* __restrict__ lens, const float* __restrict__ dacc,
            float* __restrict__ stats)
{
    int b = blockIdx.x;
    int off = 0;
    for (int i = 0; i < b; ++i) off += lens[i];
    int len = lens[b];
    const float* base = dacc + (long)off * H1c;
    float s = 0.f, ss = 0.f;
    int total = len * H1c;
    for (int i = threadIdx.x; i < total; i += 256) { float v = base[i]; s += v; ss += v * v; }
    __shared__ float rs[256], rss[256];
    rs[threadIdx.x] = s; rss[threadIdx.x] = ss;
    __syncthreads();
    for (int st = 128; st > 0; st >>= 1) {
        if (threadIdx.x < st) { rs[threadIdx.x] += rs[threadIdx.x + st]; rss[threadIdx.x] += rss[threadIdx.x + st]; }
        __syncthreads();
    }
    if (threadIdx.x == 0) {
        float m = rs[0] / (float)(LMAXc * H1c);
        float v = rss[0] / (float)(LMAXc * H1c) - m * m;
        stats[b]      = m;
        stats[32 + b] = rsqrtf(fmaxf(v, 0.f) + EPSc);
        stats[64 + b] = (float)off;
    }
}

// ---------------- BN2 apply -> LSTM2 layer-0 input, fp16, rows (t*32+b) of 128
__global__ void __launch_bounds__(256)
k_bn2_apply(const float* __restrict__ dacc, const float* __restrict__ stats,
            const int* __restrict__ lens, const float* __restrict__ g,
            const float* __restrict__ bb, _Float16* __restrict__ outA)
{
    int i = blockIdx.x * 256 + threadIdx.x;
    if (i >= R2c * 128) return;
    int rr = i >> 7, k = i & 127;
    int b = rr >> 10, p = rr & 1023;
    float y = 0.f;
    if (k < H1c) {
        int off = (int)stats[64 + b];
        float x = (p < lens[b]) ? dacc[(off + p) * H1c + k] : 0.f;
        y = (x - stats[b]) * stats[32 + b] * g[b] + bb[b];
    }
    outA[(size_t)(p * 32 + b) * 128 + k] = (_Float16)y;
}

DEVI float qsel(f32x4 a, int quad) {     // a[quad] via cndmask
    float t01 = (quad & 1) ? a[1] : a[0];
    float t23 = (quad & 1) ? a[3] : a[2];
    return (quad & 2) ? t23 : t01;
}

// fresh spin on 16 per-wave producer flags (lanes 0..15 each watch one flag).
// Contains vmcnt(0): over-drains the counted window -> always safe.
DEVI void spin_ge(const int* fl, int lane, int need)
{
    for (;;) {
        int f = 0x7fffffff;
        if (lane < 16)
            asm volatile("global_load_dword %0, %1, off sc0 sc1\n\ts_waitcnt vmcnt(0)"
                         : "+v"(f) : "v"(fl) : "memory");
        if (__all(f >= need)) break;
    }
}

// ---------------- LSTM2: all 4 layers, wavefront-pipelined across blocks.
// 32 blocks = (layer l = bx&3) x (sample group g = bx>>2, 4 samples each).
// 1024 thr / 16 waves; wave w owns N-cells [w*32, w*32+32) (nt=2 tiles of 16)
// -> weight fragments 256B/thread = 64 VGPR (fits 128-reg budget @4 w/SIMD).
// MFMA writes f32 preacts to LDS; gate stage ((sample,cell)-parallel, with
// bias from LDS) consumes them. Per wave per step EXACTLY 4 VMEM ops
// [flagstore, xload, hstore, flagload] + s_waitcnt vmcnt(4) -> ops drain with
// ~2 steps of slack. Waves 8-15 mirror the gate/publish stage (same values &
// addresses; benign) so per-wave VMEM counts stay uniform.
#define STEP(T, PAR, R, F)                                                          \
  {                                                                                 \
    f32x4 acc0 = {0.f, 0.f, 0.f, 0.f}, acc1 = {0.f, 0.f, 0.f, 0.f};                 \
    _Pragma("unroll") for (int kc = 0; kc < 4; ++kc) {                              \
        f16x8 ax = *(const f16x8*)&xp[PAR][(l16 & 3) * SH + kc * 32 + quad * 8];    \
        acc0 = __builtin_amdgcn_mfma_f32_16x16x32_f16(ax, wB[0][kc], acc0, 0, 0, 0);\
        acc1 = __builtin_amdgcn_mfma_f32_16x16x32_f16(ax, wB[1][kc], acc1, 0, 0, 0);\
    }                                                                               \
    _Pragma("unroll") for (int kc = 0; kc < 4; ++kc) {                              \
        f16x8 ah = *(const f16x8*)&av[PAR][(l16 & 3) * SH + kc * 32 + quad * 8];    \
        acc0 = __builtin_amdgcn_mfma_f32_16x16x32_f16(ah, wB[0][4 + kc], acc0, 0, 0, 0);\
        acc1 = __builtin_amdgcn_mfma_f32_16x16x32_f16(ah, wB[1][4 + kc], acc1, 0, 0, 0);\
    }                                                                               \
    pre[quad * 520 + wn0 + l16]      = qsel(acc0, quad);                            \
    pre[quad * 520 + wn0 + 16 + l16] = qsel(acc1, quad);                            \
    asm volatile("s_waitcnt vmcnt(4)" ::: "memory");                                \
    __builtin_amdgcn_sched_barrier(0);                                              \
    if (lane == 0) {                                                                \
        int fv = (T) - 1;                                                           \
        asm volatile("global_store_dword %0, %1, off sc0 sc1"                       \
                     :: "v"(myflag), "v"(fv) : "memory");                           \
    }                                                                               \
    *(unsigned*)&xp[PAR ^ 1][csam * SH + 2 * coff] = R;                             \
    barrier_lds();                                                                  \
    float gi = pre[gs * 520 + gc]       + bL[gc];                                   \
    float gf = pre[gs * 520 + 128 + gc] + bL[128 + gc];                             \
    float gg = pre[gs * 520 + 256 + gc] + bL[256 + gc];                             \
    float go = pre[gs * 520 + 384 + gc] + bL[384 + gc];                             \
    float cv = sigm(gf) * cst + sigm(gi) * tanhf_(gg);                              \
    cst = cv;                                                                       \
    float hv = sigm(go) * tanhf_(cv);                                               \
    _Float16 hf = (_Float16)hv;                                                     \
    av[PAR ^ 1][gs * SH + gc] = hf;                                                 \
    {                                                                               \
        int need = ((T) <= LMAXc - 4) ? (T) + 4 : 0;                                \
        if (!__all(lane >= 16 || F >= need)) spin_ge(sflag, lane, need);            \
    }                                                                               \
    if (l == 0)                                                                     \
        asm volatile("global_load_dword %0, %1, off" : "=v"(R) : "v"(xq) : "memory"); \
    else                                                                            \
        asm volatile("global_load_dword %0, %1, off sc0 sc1" : "=v"(R) : "v"(xq) : "memory"); \
    if ((T) < LMAXc - 4) xq += xstep;                                               \
    {   unsigned hb = (unsigned)__builtin_bit_cast(unsigned short, hf);             \
        asm volatile("global_store_short %0, %1, off sc0 sc1"                       \
                     :: "v"(hp), "v"(hb) : "memory"); }                             \
    hp += 512;                                                                      \
    if (lane < 16)                                                                  \
        asm volatile("global_load_dword %0, %1, off sc0 sc1"                        \
                     : "+v"(F) : "v"(sflag) : "memory");                            \
    barrier_lds();                                                                  \
  }

__global__ void
__attribute__((amdgpu_flat_work_group_size(1024, 1024), amdgpu_waves_per_eu(4, 4)))
k_scan2p(const _Float16* __restrict__ seqA,   // [32768][128] l0 input
         const _Float16* __restrict__ wihAll, // [4][512][128] fp16
         const _Float16* __restrict__ whhAll, // [4][512][128] fp16
         const float* __restrict__ b0,        // [512]
         const float* __restrict__ bS,        // [3][512]
         _Float16* __restrict__ hbuf,         // [4][8][1024*512] fp16 (slot 3 unread)
         int* __restrict__ flags,             // [1024]
         float* __restrict__ c2)              // [4][32][128]
{
    constexpr int SH = 144;
    __shared__ alignas(16) _Float16 av[2][4 * SH];   // h(t-1) double buffer
    __shared__ alignas(16) _Float16 xp[2][4 * SH];   // x(t) double buffer
    __shared__ float pre[4 * 520];                   // gate preacts (padded)
    __shared__ float bL[512];                        // biases

    const int bx   = blockIdx.x;
    const int l    = bx & 3;
    const int g    = bx >> 2;
    const int tid  = threadIdx.x;
    const int lane = tid & 63;
    const int w    = tid >> 6;            // wave 0..15
    const int l16  = lane & 15;
    const int quad = lane >> 4;
    const int wn0  = w * 32;              // wave's N-base
    const int gp   = tid & 511;           // gate-stage pair id (dup for tid>=512)
    const int gs   = gp >> 7;             // sample 0..3
    const int gc   = gp & 127;            // cell 0..127

    const _Float16* Wih = wihAll + (size_t)l * 512 * 128;
    const _Float16* Whh = whhAll + (size_t)l * 512 * 128;
    const float*   bptr = (l == 0) ? b0 : bS + (l - 1) * 512;

    if (tid < 512) bL[tid] = bptr[tid];

    // weights: 16 fragments (nt=2 x kc=8) = 256B/thread = 64 regs; pinned
    // into AGPRs so they sit outside arch-VGPR pressure.
    f16x8 wB[2][8];
#pragma unroll
    for (int nt = 0; nt < 2; ++nt) {
        const int n = wn0 + nt * 16 + l16;
#pragma unroll
        for (int kc = 0; kc < 4; ++kc) {
            wB[nt][kc]     = *(const f16x8*)&Wih[(size_t)n * 128 + kc * 32 + quad * 8];
            wB[nt][4 + kc] = *(const f16x8*)&Whh[(size_t)n * 128 + kc * 32 + quad * 8];
        }
    }
#pragma unroll
    for (int nt = 0; nt < 2; ++nt)
#pragma unroll
        for (int k = 0; k < 8; ++k)
            asm volatile("" : "+a"(wB[nt][k]));
    drain_vmem();
    __builtin_amdgcn_sched_barrier(0);

    // consumer-side x tile: 1KB/step = 256 dwords; ci duplicated 4x across
    // the 16 waves so vmcnt accounting stays wave-uniform.
    const int ci   = tid & 255;
    const int csam = ci >> 6;         // sample 0..3
    const int coff = ci & 63;         // dword within 128-fp16 row

    const unsigned* xq;
    int xstep;                        // dwords per t
    if (l == 0) {
        xq    = (const unsigned*)seqA + ((size_t)(g * 4 + csam)) * 64 + coff;
        xstep = 32 * 64;
    } else {
        xq    = (const unsigned*)(hbuf + ((size_t)((l - 1) * 8 + g)) * (LMAXc * 512)) + ci;
        xstep = 256;
    }

    _Float16*  hp     = hbuf + ((size_t)(l * 8 + g)) * (LMAXc * 512) + gp;
    int*       myflag = flags + (l * 8 + g) * 16 + w;
    const int* sflag  = (l == 0) ? (flags + 512 + (lane & 15))
                                 : (flags + ((l - 1) * 8 + g) * 16 + (lane & 15));

    // init h(-1) = 1, c(-1) = 1
    if (tid < 512) av[0][gs * SH + gc] = (_Float16)1.0f;
    float cst = 1.f;

    unsigned rA, rB;
    int fpreA = 0, fpreB = 0;

    // prologue: x(0)->LDS, x(1)->rA (drained), x(2)->rB (in flight),
    // 2 flag prefetches in flight. Outstanding at t=0 ph3: 3 -> vmcnt(4) ok.
    spin_ge(sflag, lane, 1);
    if (l == 0) asm volatile("global_load_dword %0, %1, off" : "=v"(rA) : "v"(xq) : "memory");
    else        asm volatile("global_load_dword %0, %1, off sc0 sc1" : "=v"(rA) : "v"(xq) : "memory");
    drain_vmem();
    __builtin_amdgcn_sched_barrier(0);
    *(unsigned*)&xp[0][csam * SH + 2 * coff] = rA;

    spin_ge(sflag, lane, 2);
    {
        const unsigned* p1 = xq + xstep;
        if (l == 0) asm volatile("global_load_dword %0, %1, off" : "=v"(rA) : "v"(p1) : "memory");
        else        asm volatile("global_load_dword %0, %1, off sc0 sc1" : "=v"(rA) : "v"(p1) : "memory");
    }
    drain_vmem();
    __builtin_amdgcn_sched_barrier(0);

    spin_ge(sflag, lane, 3);
    {
        const unsigned* p2 = xq + 2 * xstep;
        if (l == 0) asm volatile("global_load_dword %0, %1, off" : "=v"(rB) : "v"(p2) : "memory");
        else        asm volatile("global_load_dword %0, %1, off sc0 sc1" : "=v"(rB) : "v"(p2) : "memory");
    }
    if (lane < 16) {
        asm volatile("global_load_dword %0, %1, off sc0 sc1" : "+v"(fpreA) : "v"(sflag) : "memory");
        asm volatile("global_load_dword %0, %1, off sc0 sc1" : "+v"(fpreB) : "v"(sflag) : "memory");
    }
    xq += 3 * (size_t)xstep;          // -> x(3), target of step 0's prefetch
    __syncthreads();

#pragma unroll 1
    for (int t = 0; t < LMAXc; t += 2) {
        STEP(t,     0, rA, fpreA)
        STEP(t + 1, 1, rB, fpreB)
    }

    // epilogue: drain everything, publish final flag = LMAX
    drain_vmem();
    if (lane == 0) {
        int fin = LMAXc;
        asm volatile("global_store_dword %0, %1, off sc0 sc1"
                     :: "v"(myflag), "v"(fin) : "memory");
    }
    if (tid < 512)
        c2[(size_t)l * 4096 + (g * 4 + gs) * 128 + gc] = 0.25f * cst;
}

// ---------------- head: BN3 + MLP + relu(sum), single WG fp32
DEVI void bn_rows_dev(float* X, int K, const float* g, const float* bb,
                      float* mv, int tid)
{
    __syncthreads();
    if (tid < 32) {
        float s = 0.f, ss = 0.f;
        const float* r = X + tid * K;
        for (int k = 0; k < K; ++k) { float v = r[k]; s += v; ss += v * v; }
        float m = s / (float)K;
        float vv = ss / (float)K - m * m;
        mv[tid]      = m;
        mv[32 + tid] = rsqrtf(fmaxf(vv, 0.f) + EPSc);
    }
    __syncthreads();
    for (int i = tid; i < 32 * K; i += 256) {
        int b = i / K;
        X[i] = (X[i] - mv[b]) * mv[32 + b] * g[b] + bb[b];
    }
    __syncthreads();
}

DEVI void lin_dev(const float* X, int K, const float* W, const float* bias,
                  int NO, float* Y, int relu, int tid)
{
    __syncthreads();
    for (int i = tid; i < 32 * NO; i += 256) {
        int b = i / NO, j = i - b * NO;
        float a = bias[j];
        const float* xr = X + b * K;
        const float* wr = W + j * K;
        for (int k = 0; k < K; ++k) a += xr[k] * wr[k];
        Y[i] = relu ? fmaxf(a, 0.f) : a;
    }
    __syncthreads();
}

__global__ void __launch_bounds__(256)
k_head(const float* __restrict__ c2, const float* __restrict__ g3, const float* __restrict__ bb3,
       const float* w1, const float* b1, const float* w2, const float* b2,
       const float* w22, const float* b22, const float* w3, const float* b3,
       const float* w4, const float* b4, const float* w5, const float* b5,
       float* __restrict__ out)
{
    __shared__ float A[32 * 128];
    __shared__ float Bf[32 * 128];
    __shared__ float mv[64];
    const int tid = threadIdx.x;

    for (int i = tid; i < 32 * 128; i += 256)
        A[i] = c2[i] + c2[4096 + i] + c2[8192 + i] + c2[12288 + i];
    bn_rows_dev(A, 128, g3, bb3, mv, tid);
    lin_dev(A, 128, w1, b1, 128, Bf, 1, tid);
    lin_dev(Bf, 128, w2, b2, 64, A, 1, tid);
    bn_rows_dev(A, 64, g3, bb3, mv, tid);
    lin_dev(A, 64, w22, b22, 64, Bf, 1, tid);
    lin_dev(Bf, 64, w3, b3, 32, A, 1, tid);
    lin_dev(A, 32, w4, b4, 32, Bf, 1, tid);
    lin_dev(Bf, 32, w5, b5, 16, A, 0, tid);
    if (tid < 32) {
        float s = 0.f;
        for (int j = 0; j < 16; ++j) s += A[tid * 16 + j];
        out[tid] = fmaxf(s, 0.f);
    }
}

// ---------------- host
extern "C" void kernel_launch(void* const* d_in, const int* in_sizes, int n_in,
                              void* d_out, int out_size, void* d_ws, size_t ws_size,
                              hipStream_t stream)
{
    const int*   atoms  = (const int*)d_in[0];
    const int*   lens   = (const int*)d_in[2];
    const float* embw   = (const float*)d_in[5];
    const float* l1Wih0 = (const float*)d_in[6];
    const float* l1Whh0 = (const float*)d_in[7];
    const float* l1b0   = (const float*)d_in[8];
    const float* l1Wih  = (const float*)d_in[9];
    const float* l1Whh  = (const float*)d_in[10];
    const float* l1b    = (const float*)d_in[11];
    const float* l2Wih0 = (const float*)d_in[12];
    const float* l2Whh0 = (const float*)d_in[13];
    const float* l2b0   = (const float*)d_in[14];
    const float* l2Wih  = (const float*)d_in[15];
    const float* l2Whh  = (const float*)d_in[16];
    const float* l2b    = (const float*)d_in[17];
    const float* bn2g   = (const float*)d_in[18];
    const float* bn2b   = (const float*)d_in[19];
    const float* bn3g   = (const float*)d_in[20];
    const float* bn3b   = (const float*)d_in[21];
    const float* w1  = (const float*)d_in[22]; const float* b1  = (const float*)d_in[23];
    const float* w2  = (const float*)d_in[24]; const float* b2  = (const float*)d_in[25];
    const float* w22 = (const float*)d_in[26]; const float* b22 = (const float*)d_in[27];
    const float* w3  = (const float*)d_in[28]; const float* b3  = (const float*)d_in[29];
    const float* w4  = (const float*)d_in[30]; const float* b4  = (const float*)d_in[31];
    const float* w5  = (const float*)d_in[32]; const float* b5  = (const float*)d_in[33];
    float* out = (float*)d_out;

    char* base = (char*)d_ws;
    size_t off = 0;
    auto take = [&](size_t bytes) -> char* {
        char* p = base + off;
        off = (off + bytes + 255) & ~(size_t)255;
        return p;
    };
    _Float16* seq1f  = (_Float16*)take((size_t)NTc * H1c * 2);               // 63.6 MB
    float*    dacc   = (float*)take((size_t)Ntot * H1c * 4);                 // 6.4 MB
    _Float16* wcomb1 = (_Float16*)take((size_t)4 * 256 * 128 * 2);           // 256 KB
    _Float16* wih16  = (_Float16*)take((size_t)4 * 512 * 128 * 2);           // 512 KB
    _Float16* whh16  = (_Float16*)take((size_t)4 * 512 * 128 * 2);           // 512 KB
    _Float16* seqA   = (_Float16*)take((size_t)R2c * 128 * 2);               // 8.4 MB
    _Float16* hbuf   = (_Float16*)take((size_t)4 * 8 * LMAXc * 512 * 2);     // 32 MB
    int*      flags  = (int*)take(1024 * sizeof(int));
    float*    stats  = (float*)take(1024);
    float*    c2     = (float*)take((size_t)4 * 32 * 128 * 4);

    // weight preps (prepw2 also resets flags for this launch)
    k_prepw1<<<(4 * 256 * 128 + 255) / 256, 256, 0, stream>>>(l1Wih0, l1Whh0, l1Wih, l1Whh, wcomb1);
    k_prepw2<<<(2 * 4 * 512 * 128 + 255) / 256, 256, 0, stream>>>(l2Wih0, l2Wih, l2Whh0, l2Whh, wih16, whh16, flags);

    // LSTM1: embed + 4 layers fused
    k_scan1all<<<Ntot / 32, 256, 0, stream>>>(atoms, embw, wcomb1, l1b0, l1b, seq1f, dacc);

    k_bn2_stats<<<32, 256, 0, stream>>>(lens, dacc, stats);
    k_bn2_apply<<<(R2c * 128 + 255) / 256, 256, 0, stream>>>(dacc, stats, lens, bn2g, bn2b, seqA);

    // LSTM2: all 4 layers wavefront-pipelined in one kernel
    k_scan2p<<<32, 1024, 0, stream>>>(seqA, wih16, whh16, l2b0, l2b, hbuf, flags, c2);

    k_head<<<1, 256, 0, stream>>>(c2, bn3g, bn3b, w1, b1, w2, b2, w22, b22,
                                  w3, b3, w4, b4, w5, b5, out);

    (void)in_sizes; (void)n_in; (void)out_size; (void)ws_size;
}

// Round 6
// 1770.387 us; speedup vs baseline: 1.3065x; 1.3065x over previous
//
#include <hip/hip_runtime.h>

// Round 19: split k_scan2p's weight streaming across BOTH memory pipes.
//  Model (R13-R18, quantitative): step ~= weightKB/0.128 + ~500cy serial ->
//  the scan is VMEM-bound streaming 256KB of weights per step from L1/L2.
//  4 register-residency attempts failed (compiler streams regardless).
//  Fix: Whh gates 0-2 (96KB) staged once into LDS (contiguous-per-
//  instruction layout -> 0 bank conflicts), read per step via ds_read_b128
//  (~85B/cy pipe) CONCURRENTLY with VMEM streaming Wih + Whh gate 3
//  (160KB, ~128B/cy). Predicted step ~2270 -> ~1500cy.
//  Protocol/shape byte-identical to R17 otherwise; AGPR pins removed.

typedef _Float16 f16x8  __attribute__((ext_vector_type(8)));
typedef float    f32x4  __attribute__((ext_vector_type(4)));

#define DEVI static __device__ __forceinline__

constexpr int   T1c   = 20;
constexpr int   EMBc  = 32;
constexpr int   H1c   = 64;
constexpr int   LMAXc = 1024;
constexpr int   VOCABc= 85;
constexpr int   Ntot  = 24832;           // sum of lengths
constexpr int   NTc   = Ntot * T1c;      // 496640
constexpr int   R2c   = 32 * LMAXc;      // 32768
constexpr float EPSc  = 1e-5f;

DEVI float sigm(float x)   { return 1.f / (1.f + __expf(-x)); }
DEVI float tanhf_(float x) { return 1.f - 2.f / (1.f + __expf(2.f * x)); }

DEVI void barrier_lds() {                // barrier draining LDS only (not vmcnt)
    asm volatile("s_waitcnt lgkmcnt(0)\n\ts_barrier" ::: "memory");
}
DEVI void drain_vmem() {
    asm volatile("s_waitcnt vmcnt(0)" ::: "memory");
}

// ---------------- prep: LSTM1 combined fp16 [4][256][128] = [Wih|pad|Whh]
__global__ void __launch_bounds__(256)
k_prepw1(const float* __restrict__ Wih0, const float* __restrict__ Whh0,
         const float* __restrict__ WihS, const float* __restrict__ WhhS,
         _Float16* __restrict__ out)
{
    int i = blockIdx.x * 256 + threadIdx.x;
    if (i >= 4 * 256 * 128) return;
    int l = i >> 15, rem = i & 32767, r = rem >> 7, k = rem & 127;
    float v;
    if (l == 0) {
        if (k < 32)      v = Wih0[r * 32 + k];
        else if (k < 64) v = 0.f;
        else             v = Whh0[r * 64 + (k - 64)];
    } else {
        if (k < 64)      v = WihS[((l - 1) * 256 + r) * 64 + k];
        else             v = WhhS[((l - 1) * 256 + r) * 64 + (k - 64)];
    }
    out[i] = (_Float16)v;
}

// ---------------- prep: LSTM2 wih16 [4][512][128] (l0 zero-padded) + whh16
// also resets pipeline flags: [0..255] real -> 0, [256..511] dummy -> INT_MAX
__global__ void __launch_bounds__(256)
k_prepw2(const float* __restrict__ Wih0, const float* __restrict__ WihS,
         const float* __restrict__ Whh0, const float* __restrict__ WhhS,
         _Float16* __restrict__ wih, _Float16* __restrict__ whh,
         int* __restrict__ flags)
{
    int i = blockIdx.x * 256 + threadIdx.x;
    if (i < 512) flags[i] = (i < 256) ? 0 : 0x7fffffff;
    if (i >= 2 * 4 * 512 * 128) return;
    int half = i >> 18, rem = i & 262143;
    int l = rem >> 16, r = (rem >> 7) & 511, k = rem & 127;
    if (half == 0) {
        float v = (l == 0) ? ((k < 64) ? Wih0[r * 64 + k] : 0.f)
                           : WihS[((l - 1) * 512 + r) * 128 + k];
        wih[rem] = (_Float16)v;
    } else {
        float v = (l == 0) ? Whh0[r * 128 + k]
                           : WhhS[((l - 1) * 512 + r) * 128 + k];
        whh[rem] = (_Float16)v;
    }
}

// ---------------- LSTM1: embed + 4 layers fused, one kernel. 32 samples/WG,
// 256 thr = 4 waves. Uniform K=128 body ([x(64, l0 zero-padded)|h(64)]).
__global__ void __launch_bounds__(256)
k_scan1all(const int* __restrict__ atoms, const float* __restrict__ ew,
           const _Float16* __restrict__ W16all,
           const float* __restrict__ b0, const float* __restrict__ bS,
           _Float16* __restrict__ seq, float* __restrict__ dacc)
{
    constexpr int SX = 136;
    __shared__ alignas(16) _Float16 xh[32 * SX];     // 8.7 KB
    __shared__ float ewl[VOCABc * EMBc];             // 10.9 KB
    __shared__ int   aidl[32 * T1c];                 // 2.5 KB

    const int tid  = threadIdx.x;
    const int lane = tid & 63;
    const int wv   = tid >> 6;
    const int l16  = lane & 15;
    const int quad = lane >> 4;
    const int n0   = blockIdx.x * 32;
    const int d    = wv * 16 + l16;

    for (int i = tid; i < VOCABc * EMBc; i += 256) ewl[i] = ew[i];
    for (int i = tid; i < 32 * T1c; i += 256) aidl[i] = atoms[n0 * T1c + i];

    float daccv[2][4];
#pragma unroll
    for (int mt = 0; mt < 2; ++mt)
#pragma unroll
        for (int r = 0; r < 4; ++r) daccv[mt][r] = 0.f;

    __syncthreads();

#pragma unroll 1
    for (int l = 0; l < 4; ++l) {
        const _Float16* W16  = W16all + (size_t)l * 256 * 128;
        const float*    bptr = (l == 0) ? b0 : bS + (l - 1) * 256;

        float bias[4];
#pragma unroll
        for (int g = 0; g < 4; ++g) bias[g] = bptr[g * 64 + d];

        f16x8 wF[4][4];
#pragma unroll
        for (int kc = 0; kc < 4; ++kc) {
            const int kb = kc * 32 + quad * 8;
#pragma unroll
            for (int g = 0; g < 4; ++g)
                wF[kc][g] = *(const f16x8*)&W16[(size_t)(g * 64 + d) * 128 + kb];
        }

        f32x4 c[2];
        c[0] = {1.f, 1.f, 1.f, 1.f};
        c[1] = {1.f, 1.f, 1.f, 1.f};

        drain_vmem();            // prev layer's seq stores complete (same CU)
        __syncthreads();

        // h(t=-1) = 1; layer 0: zero x cols [32,64) once (zero weights there)
#pragma unroll
        for (int mt = 0; mt < 2; ++mt)
#pragma unroll
            for (int r = 0; r < 4; ++r)
                xh[(mt * 16 + quad * 4 + r) * SX + 64 + d] = (_Float16)1.0f;
        if (l == 0)
            for (int idx = tid; idx < 32 * 32; idx += 256) {
                int s = idx >> 5, e = idx & 31;
                xh[s * SX + 32 + e] = (_Float16)0.f;
            }

#pragma unroll 1
        for (int t = 0; t < T1c; ++t) {
            if (l == 0) {
                for (int idx = tid; idx < 32 * 32; idx += 256) {
                    int s = idx >> 5, e = idx & 31;
                    int id = aidl[s * T1c + t];
                    xh[s * SX + e] = (_Float16)(ewl[id * EMBc + e] * (float)id);
                }
            } else {
                for (int idx = tid; idx < 32 * 8; idx += 256) {
                    int s = idx >> 3, k8 = idx & 7;
                    *(f16x8*)&xh[s * SX + k8 * 8] =
                        *(const f16x8*)&seq[((size_t)(n0 + s) * T1c + t) * H1c + k8 * 8];
                }
            }
            __syncthreads();

            f32x4 acc[2][4];
#pragma unroll
            for (int mt = 0; mt < 2; ++mt)
#pragma unroll
                for (int g = 0; g < 4; ++g)
                    acc[mt][g] = {bias[g], bias[g], bias[g], bias[g]};

#pragma unroll
            for (int kc = 0; kc < 4; ++kc) {
                const int kb = kc * 32 + quad * 8;
                f16x8 ah[2];
#pragma unroll
                for (int mt = 0; mt < 2; ++mt)
                    ah[mt] = *(const f16x8*)&xh[(mt * 16 + l16) * SX + kb];
#pragma unroll
                for (int g = 0; g < 4; ++g)
#pragma unroll
                    for (int mt = 0; mt < 2; ++mt)
                        acc[mt][g] = __builtin_amdgcn_mfma_f32_16x16x32_f16(ah[mt], wF[kc][g], acc[mt][g], 0, 0, 0);
            }
            __syncthreads();

#pragma unroll
            for (int mt = 0; mt < 2; ++mt)
#pragma unroll
                for (int r = 0; r < 4; ++r) {
                    float iv = sigm(acc[mt][0][r]);
                    float fv = sigm(acc[mt][1][r]);
                    float gv = tanhf_(acc[mt][2][r]);
                    float ov = sigm(acc[mt][3][r]);
                    float cv = fv * c[mt][r] + iv * gv;
                    c[mt][r] = cv;
                    float hv = ov * tanhf_(cv);
                    _Float16 hf = (_Float16)hv;
                    int s = mt * 16 + quad * 4 + r;
                    xh[s * SX + 64 + d] = hf;
                    if (l < 3)
                        seq[((size_t)(n0 + s) * T1c + t) * H1c + d] = hf;
                    if (t == T1c - 1)
                        daccv[mt][r] += 0.25f * (hv + cv);
                }
        }
    }
#pragma unroll
    for (int mt = 0; mt < 2; ++mt)
#pragma unroll
        for (int r = 0; r < 4; ++r) {
            int s = mt * 16 + quad * 4 + r;
            dacc[(size_t)(n0 + s) * H1c + d] = daccv[mt][r];
        }
}

// ---------------- BN2 stats
__global__ void __launch_bounds__(256)
k_bn2_stats(const int* __restrict__ lens, const float* __restrict__ dacc,
            float* __restrict__ stats)
{
    int b = blockIdx.x;
    int off = 0;
    for (int i = 0; i < b; ++i) off += lens[i];
    int len = lens[b];
    const float* base = dacc + (long)off * H1c;
    float s = 0.f, ss = 0.f;
    int total = len * H1c;
    for (int i = threadIdx.x; i < total; i += 256) { float v = base[i]; s += v; ss += v * v; }
    __shared__ float rs[256], rss[256];
    rs[threadIdx.x] = s; rss[threadIdx.x] = ss;
    __syncthreads();
    for (int st = 128; st > 0; st >>= 1) {
        if (threadIdx.x < st) { rs[threadIdx.x] += rs[threadIdx.x + st]; rss[threadIdx.x] += rss[threadIdx.x + st]; }
        __syncthreads();
    }
    if (threadIdx.x == 0) {
        float m = rs[0] / (float)(LMAXc * H1c);
        float v = rss[0] / (float)(LMAXc * H1c) - m * m;
        stats[b]      = m;
        stats[32 + b] = rsqrtf(fmaxf(v, 0.f) + EPSc);
        stats[64 + b] = (float)off;
    }
}

// ---------------- BN2 apply -> LSTM2 layer-0 input, fp16, rows (t*32+b) of 128
__global__ void __launch_bounds__(256)
k_bn2_apply(const float* __restrict__ dacc, const float* __restrict__ stats,
            const int* __restrict__ lens, const float* __restrict__ g,
            const float* __restrict__ bb, _Float16* __restrict__ outA)
{
    int i = blockIdx.x * 256 + threadIdx.x;
    if (i >= R2c * 128) return;
    int rr = i >> 7, k = i & 127;
    int b = rr >> 10, p = rr & 1023;
    float y = 0.f;
    if (k < H1c) {
        int off = (int)stats[64 + b];
        float x = (p < lens[b]) ? dacc[(off + p) * H1c + k] : 0.f;
        y = (x - stats[b]) * stats[32 + b] * g[b] + bb[b];
    }
    outA[(size_t)(p * 32 + b) * 128 + k] = (_Float16)y;
}

DEVI float qsel(f32x4 a, int quad) {     // a[quad] via cndmask
    float t01 = (quad & 1) ? a[1] : a[0];
    float t23 = (quad & 1) ? a[3] : a[2];
    return (quad & 2) ? t23 : t01;
}

// fresh spin on 8 per-wave producer flags (lanes 0..7 each watch one flag).
// Contains vmcnt(0): over-drains the counted window -> always safe.
DEVI void spin_ge(const int* fl, int lane, int need)
{
    for (;;) {
        int f = 0x7fffffff;
        if (lane < 8)
            asm volatile("global_load_dword %0, %1, off sc0 sc1\n\ts_waitcnt vmcnt(0)"
                         : "+v"(f) : "v"(fl) : "memory");
        if (__all(f >= need)) break;
    }
}

// ---------------- LSTM2: all 4 layers, wavefront-pipelined across blocks.
// 32 blocks = (layer l = bx&3) x (sample group g = bx>>2, 4 samples each).
// Per step, per wave, EXACTLY 4 VMEM ops in order [flagstore, xload, hstore,
// flagload]; ph3's s_waitcnt vmcnt(4) drains the ops issued 2 steps ago ->
// ~2 steps of slack vs coherent latency. Whh gates 0-2 come from LDS
// (ds_read_b128, conflict-free contiguous layout) while Wih + Whh gate 3
// stream on the VMEM pipe -> the two pipes overlap.
#define STEP(T, PAR, R, F)                                                          \
  {                                                                                 \
    f32x4 acc[4];                                                                   \
    _Pragma("unroll") for (int g4 = 0; g4 < 4; ++g4)                                \
        acc[g4] = {bia[g4], bia[g4], bia[g4], bia[g4]};                             \
    _Pragma("unroll") for (int kc = 0; kc < 4; ++kc) {                              \
        f16x8 ax = *(const f16x8*)&xp[PAR][(l16 & 3) * SH + kc * 32 + quad * 8];    \
        _Pragma("unroll") for (int g4 = 0; g4 < 4; ++g4)                            \
            acc[g4] = __builtin_amdgcn_mfma_f32_16x16x32_f16(ax, wI[g4][kc], acc[g4], 0, 0, 0); \
    }                                                                               \
    _Pragma("unroll") for (int kc = 0; kc < 4; ++kc) {                              \
        f16x8 ah = *(const f16x8*)&av[PAR][(l16 & 3) * SH + kc * 32 + quad * 8];    \
        acc[0] = __builtin_amdgcn_mfma_f32_16x16x32_f16(ah, *(const f16x8*)&whhL[(0 * 4 + kc) * 4096 + whbase], acc[0], 0, 0, 0); \
        acc[1] = __builtin_amdgcn_mfma_f32_16x16x32_f16(ah, *(const f16x8*)&whhL[(1 * 4 + kc) * 4096 + whbase], acc[1], 0, 0, 0); \
        acc[2] = __builtin_amdgcn_mfma_f32_16x16x32_f16(ah, *(const f16x8*)&whhL[(2 * 4 + kc) * 4096 + whbase], acc[2], 0, 0, 0); \
        acc[3] = __builtin_amdgcn_mfma_f32_16x16x32_f16(ah, wH3[kc], acc[3], 0, 0, 0); \
    }                                                                               \
    asm volatile("s_waitcnt vmcnt(4)" ::: "memory");                                \
    __builtin_amdgcn_sched_barrier(0);                                              \
    if (lane == 0) {                                                                \
        int fv = (T) - 1;                                                           \
        asm volatile("global_store_dword %0, %1, off sc0 sc1"                       \
                     :: "v"(myflag), "v"(fv) : "memory");                           \
    }                                                                               \
    *(unsigned*)&xp[PAR ^ 1][csam * SH + 2 * coff] = R;                             \
    float gi = qsel(acc[0], quad);                                                  \
    float gf = qsel(acc[1], quad);                                                  \
    float gg = qsel(acc[2], quad);                                                  \
    float go = qsel(acc[3], quad);                                                  \
    float cv = sigm(gf) * cst + sigm(gi) * tanhf_(gg);                              \
    cst = cv;                                                                       \
    float hv = sigm(go) * tanhf_(cv);                                               \
    _Float16 hf = (_Float16)hv;                                                     \
    av[PAR ^ 1][quad * SH + cell] = hf;                                             \
    {                                                                               \
        int need = ((T) <= LMAXc - 4) ? (T) + 4 : 0;                                \
        if (!__all(lane >= 8 || F >= need)) spin_ge(sflag, lane, need);             \
    }                                                                               \
    if (l == 0)                                                                     \
        asm volatile("global_load_dword %0, %1, off" : "=v"(R) : "v"(xq) : "memory"); \
    else                                                                            \
        asm volatile("global_load_dword %0, %1, off sc0 sc1" : "=v"(R) : "v"(xq) : "memory"); \
    if ((T) < LMAXc - 4) xq += xstep;                                               \
    {   unsigned hb = (unsigned)__builtin_bit_cast(unsigned short, hf);             \
        asm volatile("global_store_short %0, %1, off sc0 sc1"                       \
                     :: "v"(hp), "v"(hb) : "memory"); }                             \
    hp += 512;                                                                      \
    if (lane < 8)                                                                   \
        asm volatile("global_load_dword %0, %1, off sc0 sc1"                        \
                     : "+v"(F) : "v"(sflag) : "memory");                            \
    barrier_lds();                                                                  \
  }

__global__ void
__attribute__((amdgpu_flat_work_group_size(512, 512), amdgpu_waves_per_eu(2, 2)))
k_scan2p(const _Float16* __restrict__ seqA,   // [32768][128] l0 input
         const _Float16* __restrict__ wihAll, // [4][512][128] fp16
         const _Float16* __restrict__ whhAll, // [4][512][128] fp16
         const float* __restrict__ b0,        // [512]
         const float* __restrict__ bS,        // [3][512]
         _Float16* __restrict__ hbuf,         // [4][8][1024*512] fp16 (slot 3 unread)
         int* __restrict__ flags,             // [512]
         float* __restrict__ c2)              // [4][32][128]
{
    constexpr int SH = 144;
    __shared__ alignas(16) _Float16 av[2][4 * SH];   // h(t-1) double buffer
    __shared__ alignas(16) _Float16 xp[2][4 * SH];   // x(t) double buffer
    __shared__ alignas(16) _Float16 whhL[3 * 4 * 4096]; // Whh gates 0-2: 96KB

    const int bx   = blockIdx.x;
    const int l    = bx & 3;
    const int g    = bx >> 2;
    const int tid  = threadIdx.x;
    const int lane = tid & 63;
    const int w    = tid >> 6;
    const int l16  = lane & 15;
    const int quad = lane >> 4;
    const int cell = w * 16 + l16;
    const int whbase = (w * 64 + lane) * 8;   // fp16 units; per-(g4,kc) stride 4096

    const _Float16* Wih = wihAll + (size_t)l * 512 * 128;
    const _Float16* Whh = whhAll + (size_t)l * 512 * 128;
    const float*   bptr = (l == 0) ? b0 : bS + (l - 1) * 512;

    // stage Whh gates 0-2 into LDS, contiguous per (g4,kc,w) instruction:
    // chunk c = ((g4*4+kc)*8 + w)*64 + lane  ->  whhL[c*8 .. c*8+8)
    for (int c = tid; c < 6144; c += 512) {
        int g4 = c >> 11;
        int r  = c & 2047;
        int kc = r >> 9;
        int r2 = r & 511;
        int wv2 = r2 >> 6;
        int ln  = r2 & 63;
        int row = g4 * 128 + wv2 * 16 + (ln & 15);
        *(f16x8*)&whhL[(size_t)c * 8] =
            *(const f16x8*)&Whh[(size_t)row * 128 + kc * 32 + (ln >> 4) * 8];
    }

    // VMEM-streamed weights: Wih all gates + Whh gate 3 (compiler schedules)
    f16x8 wI[4][4], wH3[4];
    float bia[4];
#pragma unroll
    for (int g4 = 0; g4 < 4; ++g4) {
#pragma unroll
        for (int kc = 0; kc < 4; ++kc)
            wI[g4][kc] = *(const f16x8*)&Wih[(size_t)(g4 * 128 + cell) * 128 + kc * 32 + quad * 8];
        bia[g4] = bptr[g4 * 128 + cell];
    }
#pragma unroll
    for (int kc = 0; kc < 4; ++kc)
        wH3[kc] = *(const f16x8*)&Whh[(size_t)(3 * 128 + cell) * 128 + kc * 32 + quad * 8];

    // consumer-side x tile: 1KB/step = 256 dwords; all 512 threads load
    // (tid>=256 duplicate) so vmcnt accounting is wave-uniform.
    const int ci   = tid & 255;
    const int csam = ci >> 6;         // sample 0..3
    const int coff = ci & 63;         // dword within 128-fp16 row

    const unsigned* xq;
    int xstep;                        // dwords per t
    if (l == 0) {
        xq    = (const unsigned*)seqA + ((size_t)(g * 4 + csam)) * 64 + coff;
        xstep = 32 * 64;
    } else {
        xq    = (const unsigned*)(hbuf + ((size_t)((l - 1) * 8 + g)) * (LMAXc * 512)) + ci;
        xstep = 256;
    }

    _Float16*  hp     = hbuf + ((size_t)(l * 8 + g)) * (LMAXc * 512) + quad * 128 + cell;
    int*       myflag = flags + (l * 8 + g) * 8 + w;
    const int* sflag  = (l == 0) ? (flags + 256 + (lane & 7))
                                 : (flags + ((l - 1) * 8 + g) * 8 + (lane & 7));

    // init h(-1) = 1, c(-1) = 1
    { int s = tid >> 7, e = tid & 127; av[0][s * SH + e] = (_Float16)1.0f; }
    float cst = 1.f;

    unsigned rA, rB;
    int fpreA = 0, fpreB = 0;

    // prologue: x(0)->LDS, x(1)->rA (drained), x(2)->rB (in flight),
    // 2 flag prefetches in flight. Outstanding at t=0 ph3: 3 -> vmcnt(4) ok.
    spin_ge(sflag, lane, 1);
    if (l == 0) asm volatile("global_load_dword %0, %1, off" : "=v"(rA) : "v"(xq) : "memory");
    else        asm volatile("global_load_dword %0, %1, off sc0 sc1" : "=v"(rA) : "v"(xq) : "memory");
    drain_vmem();
    __builtin_amdgcn_sched_barrier(0);
    *(unsigned*)&xp[0][csam * SH + 2 * coff] = rA;

    spin_ge(sflag, lane, 2);
    {
        const unsigned* p1 = xq + xstep;
        if (l == 0) asm volatile("global_load_dword %0, %1, off" : "=v"(rA) : "v"(p1) : "memory");
        else        asm volatile("global_load_dword %0, %1, off sc0 sc1" : "=v"(rA) : "v"(p1) : "memory");
    }
    drain_vmem();
    __builtin_amdgcn_sched_barrier(0);

    spin_ge(sflag, lane, 3);
    {
        const unsigned* p2 = xq + 2 * xstep;
        if (l == 0) asm volatile("global_load_dword %0, %1, off" : "=v"(rB) : "v"(p2) : "memory");
        else        asm volatile("global_load_dword %0, %1, off sc0 sc1" : "=v"(rB) : "v"(p2) : "memory");
    }
    if (lane < 8) {
        asm volatile("global_load_dword %0, %1, off sc0 sc1" : "+v"(fpreA) : "v"(sflag) : "memory");
        asm volatile("global_load_dword %0, %1, off sc0 sc1" : "+v"(fpreB) : "v"(sflag) : "memory");
    }
    xq += 3 * (size_t)xstep;          // -> x(3), target of step 0's prefetch
    __syncthreads();

#pragma unroll 1
    for (int t = 0; t < LMAXc; t += 2) {
        STEP(t,     0, rA, fpreA)
        STEP(t + 1, 1, rB, fpreB)
    }

    // epilogue: drain everything, publish final flag = LMAX
    drain_vmem();
    if (lane == 0) {
        int fin = LMAXc;
        asm volatile("global_store_dword %0, %1, off sc0 sc1"
                     :: "v"(myflag), "v"(fin) : "memory");
    }
    c2[(size_t)l * 4096 + (g * 4 + quad) * 128 + cell] = 0.25f * cst;
}

// ---------------- head: BN3 + MLP + relu(sum), single WG fp32
DEVI void bn_rows_dev(float* X, int K, const float* g, const float* bb,
                      float* mv, int tid)
{
    __syncthreads();
    if (tid < 32) {
        float s = 0.f, ss = 0.f;
        const float* r = X + tid * K;
        for (int k = 0; k < K; ++k) { float v = r[k]; s += v; ss += v * v; }
        float m = s / (float)K;
        float vv = ss / (float)K - m * m;
        mv[tid]      = m;
        mv[32 + tid] = rsqrtf(fmaxf(vv, 0.f) + EPSc);
    }
    __syncthreads();
    for (int i = tid; i < 32 * K; i += 256) {
        int b = i / K;
        X[i] = (X[i] - mv[b]) * mv[32 + b] * g[b] + bb[b];
    }
    __syncthreads();
}

DEVI void lin_dev(const float* X, int K, const float* W, const float* bias,
                  int NO, float* Y, int relu, int tid)
{
    __syncthreads();
    for (int i = tid; i < 32 * NO; i += 256) {
        int b = i / NO, j = i - b * NO;
        float a = bias[j];
        const float* xr = X + b * K;
        const float* wr = W + j * K;
        for (int k = 0; k < K; ++k) a += xr[k] * wr[k];
        Y[i] = relu ? fmaxf(a, 0.f) : a;
    }
    __syncthreads();
}

__global__ void __launch_bounds__(256)
k_head(const float* __restrict__ c2, const float* __restrict__ g3, const float* __restrict__ bb3,
       const float* w1, const float* b1, const float* w2, const float* b2,
       const float* w22, const float* b22, const float* w3, const float* b3,
       const float* w4, const float* b4, const float* w5, const float* b5,
       float* __restrict__ out)
{
    __shared__ float A[32 * 128];
    __shared__ float Bf[32 * 128];
    __shared__ float mv[64];
    const int tid = threadIdx.x;

    for (int i = tid; i < 32 * 128; i += 256)
        A[i] = c2[i] + c2[4096 + i] + c2[8192 + i] + c2[12288 + i];
    bn_rows_dev(A, 128, g3, bb3, mv, tid);
    lin_dev(A, 128, w1, b1, 128, Bf, 1, tid);
    lin_dev(Bf, 128, w2, b2, 64, A, 1, tid);
    bn_rows_dev(A, 64, g3, bb3, mv, tid);
    lin_dev(A, 64, w22, b22, 64, Bf, 1, tid);
    lin_dev(Bf, 64, w3, b3, 32, A, 1, tid);
    lin_dev(A, 32, w4, b4, 32, Bf, 1, tid);
    lin_dev(Bf, 32, w5, b5, 16, A, 0, tid);
    if (tid < 32) {
        float s = 0.f;
        for (int j = 0; j < 16; ++j) s += A[tid * 16 + j];
        out[tid] = fmaxf(s, 0.f);
    }
}

// ---------------- host
extern "C" void kernel_launch(void* const* d_in, const int* in_sizes, int n_in,
                              void* d_out, int out_size, void* d_ws, size_t ws_size,
                              hipStream_t stream)
{
    const int*   atoms  = (const int*)d_in[0];
    const int*   lens   = (const int*)d_in[2];
    const float* embw   = (const float*)d_in[5];
    const float* l1Wih0 = (const float*)d_in[6];
    const float* l1Whh0 = (const float*)d_in[7];
    const float* l1b0   = (const float*)d_in[8];
    const float* l1Wih  = (const float*)d_in[9];
    const float* l1Whh  = (const float*)d_in[10];
    const float* l1b    = (const float*)d_in[11];
    const float* l2Wih0 = (const float*)d_in[12];
    const float* l2Whh0 = (const float*)d_in[13];
    const float* l2b0   = (const float*)d_in[14];
    const float* l2Wih  = (const float*)d_in[15];
    const float* l2Whh  = (const float*)d_in[16];
    const float* l2b    = (const float*)d_in[17];
    const float* bn2g   = (const float*)d_in[18];
    const float* bn2b   = (const float*)d_in[19];
    const float* bn3g   = (const float*)d_in[20];
    const float* bn3b   = (const float*)d_in[21];
    const float* w1  = (const float*)d_in[22]; const float* b1  = (const float*)d_in[23];
    const float* w2  = (const float*)d_in[24]; const float* b2  = (const float*)d_in[25];
    const float* w22 = (const float*)d_in[26]; const float* b22 = (const float*)d_in[27];
    const float* w3  = (const float*)d_in[28]; const float* b3  = (const float*)d_in[29];
    const float* w4  = (const float*)d_in[30]; const float* b4  = (const float*)d_in[31];
    const float* w5  = (const float*)d_in[32]; const float* b5  = (const float*)d_in[33];
    float* out = (float*)d_out;

    char* base = (char*)d_ws;
    size_t off = 0;
    auto take = [&](size_t bytes) -> char* {
        char* p = base + off;
        off = (off + bytes + 255) & ~(size_t)255;
        return p;
    };
    _Float16* seq1f  = (_Float16*)take((size_t)NTc * H1c * 2);               // 63.6 MB
    float*    dacc   = (float*)take((size_t)Ntot * H1c * 4);                 // 6.4 MB
    _Float16* wcomb1 = (_Float16*)take((size_t)4 * 256 * 128 * 2);           // 256 KB
    _Float16* wih16  = (_Float16*)take((size_t)4 * 512 * 128 * 2);           // 512 KB
    _Float16* whh16  = (_Float16*)take((size_t)4 * 512 * 128 * 2);           // 512 KB
    _Float16* seqA   = (_Float16*)take((size_t)R2c * 128 * 2);               // 8.4 MB
    _Float16* hbuf   = (_Float16*)take((size_t)4 * 8 * LMAXc * 512 * 2);     // 32 MB
    int*      flags  = (int*)take(512 * sizeof(int));
    float*    stats  = (float*)take(1024);
    float*    c2     = (float*)take((size_t)4 * 32 * 128 * 4);

    // weight preps (prepw2 also resets flags for this launch)
    k_prepw1<<<(4 * 256 * 128 + 255) / 256, 256, 0, stream>>>(l1Wih0, l1Whh0, l1Wih, l1Whh, wcomb1);
    k_prepw2<<<(2 * 4 * 512 * 128 + 255) / 256, 256, 0, stream>>>(l2Wih0, l2Wih, l2Whh0, l2Whh, wih16, whh16, flags);

    // LSTM1: embed + 4 layers fused
    k_scan1all<<<Ntot / 32, 256, 0, stream>>>(atoms, embw, wcomb1, l1b0, l1b, seq1f, dacc);

    k_bn2_stats<<<32, 256, 0, stream>>>(lens, dacc, stats);
    k_bn2_apply<<<(R2c * 128 + 255) / 256, 256, 0, stream>>>(dacc, stats, lens, bn2g, bn2b, seqA);

    // LSTM2: all 4 layers wavefront-pipelined in one kernel
    k_scan2p<<<32, 512, 0, stream>>>(seqA, wih16, whh16, l2b0, l2b, hbuf, flags, c2);

    k_head<<<1, 256, 0, stream>>>(c2, bn3g, bn3b, w1, b1, w2, b2, w22, b22,
                                  w3, b3, w4, b4, w5, b5, out);

    (void)in_sizes; (void)n_in; (void)out_size; (void)ws_size;
}